// Round 2
// 537.593 us; speedup vs baseline: 1.0361x; 1.0361x over previous
//
#include <hip/hip_runtime.h>

#define NPTS   1000000
#define NFEAT  64
#define GRIDN  100
#define NBINS  1000000   // GRIDN^3

#define SCAN_B    256    // threads per scan block
#define SCAN_I    4      // items per thread
#define SCAN_TILE 1024   // SCAN_B * SCAN_I
#define NBLK      977    // ceil(NBINS / SCAN_TILE)

typedef float f4 __attribute__((ext_vector_type(4)));

// --- 1. histogram: 4 points/thread, int4 coalesced coors+keys ---
__global__ __launch_bounds__(256) void k_count(const int4* __restrict__ coors4,
                                               int4* __restrict__ keys4,
                                               int* __restrict__ count, int nq) {
    int t = blockIdx.x * blockDim.x + threadIdx.x;
    if (t >= nq) return;                          // nq = n/4
    int4 a = coors4[3 * t + 0];
    int4 b = coors4[3 * t + 1];
    int4 c = coors4[3 * t + 2];
    int k0 = (a.x * GRIDN + a.y) * GRIDN + a.z;
    int k1 = (a.w * GRIDN + b.x) * GRIDN + b.y;
    int k2 = (b.z * GRIDN + b.w) * GRIDN + c.x;
    int k3 = (c.y * GRIDN + c.z) * GRIDN + c.w;
    keys4[t] = make_int4(k0, k1, k2, k3);
    atomicAdd(&count[k0], 1);
    atomicAdd(&count[k1], 1);
    atomicAdd(&count[k2], 1);
    atomicAdd(&count[k3], 1);
}

// --- 2a. block totals only (occupancy, count) ---
__global__ __launch_bounds__(256) void k_scan1(const int4* __restrict__ count4,
                                               int* __restrict__ blkOcc,
                                               int* __restrict__ blkCnt) {
    __shared__ int sO[SCAN_B], sC[SCAN_B];
    int tid  = threadIdx.x;
    int base = blockIdx.x * SCAN_TILE + tid * SCAN_I;
    int tO = 0, tC = 0;
    if (base < NBINS) {                          // NBINS % 4 == 0 -> whole int4 valid
        int4 v = count4[base >> 2];
        tO = (v.x > 0) + (v.y > 0) + (v.z > 0) + (v.w > 0);
        tC = v.x + v.y + v.z + v.w;
    }
    sO[tid] = tO; sC[tid] = tC;
    __syncthreads();
    for (int ofs = SCAN_B / 2; ofs > 0; ofs >>= 1) {
        if (tid < ofs) { sO[tid] += sO[tid + ofs]; sC[tid] += sC[tid + ofs]; }
        __syncthreads();
    }
    if (tid == 0) { blkOcc[blockIdx.x] = sO[0]; blkCnt[blockIdx.x] = sC[0]; }
}

// --- 2b. single-block scan of block totals -> exclusive offsets; M total ---
__global__ __launch_bounds__(1024) void k_scan2(int* __restrict__ blkOcc,
                                                int* __restrict__ blkCnt,
                                                int* __restrict__ m_dev) {
    __shared__ int sO[1024], sC[1024];
    int tid = threadIdx.x;
    int vO = (tid < NBLK) ? blkOcc[tid] : 0;
    int vC = (tid < NBLK) ? blkCnt[tid] : 0;
    sO[tid] = vO; sC[tid] = vC;
    __syncthreads();
    for (int ofs = 1; ofs < 1024; ofs <<= 1) {
        int a = 0, b = 0;
        if (tid >= ofs) { a = sO[tid - ofs]; b = sC[tid - ofs]; }
        __syncthreads();
        sO[tid] += a; sC[tid] += b;
        __syncthreads();
    }
    if (tid < NBLK) {
        blkOcc[tid] = sO[tid] - vO;              // exclusive
        blkCnt[tid] = sC[tid] - vC;
    }
    if (tid == 1023) *m_dev = sO[1023];          // total occupied voxels M
}

// --- 2c. local dual scan + global offsets; emit pstart, rankstart, rowinfo.xy ---
// rankstart[bin] = (rank << 32) | (cnt << 20) | start   (start,rank < 2^20, cnt < 2^12)
// rowinfo[r]     = { start, bin | cnt<<20, p0 (by k_fill), p1 (by k_fill) }
__global__ __launch_bounds__(256) void k_scan3(const int4* __restrict__ count4,
                                               int4* __restrict__ pstart4,
                                               const int* __restrict__ blkOcc,
                                               const int* __restrict__ blkCnt,
                                               long long* __restrict__ rankstart,
                                               int4* __restrict__ rowinfo) {
    __shared__ int sO[SCAN_B], sC[SCAN_B];
    int tid  = threadIdx.x;
    int base = blockIdx.x * SCAN_TILE + tid * SCAN_I;
    int4 v = make_int4(0, 0, 0, 0);
    if (base < NBINS) v = count4[base >> 2];
    int c[SCAN_I] = {v.x, v.y, v.z, v.w};
    int locO[SCAN_I], locC[SCAN_I];
    int tO = 0, tC = 0;
    #pragma unroll
    for (int i = 0; i < SCAN_I; ++i) {
        locO[i] = tO; locC[i] = tC;
        tO += (c[i] > 0) ? 1 : 0;
        tC += c[i];
    }
    sO[tid] = tO; sC[tid] = tC;
    __syncthreads();
    for (int ofs = 1; ofs < SCAN_B; ofs <<= 1) {   // Hillis-Steele inclusive
        int a = 0, b = 0;
        if (tid >= ofs) { a = sO[tid - ofs]; b = sC[tid - ofs]; }
        __syncthreads();
        sO[tid] += a; sC[tid] += b;
        __syncthreads();
    }
    if (base >= NBINS) return;
    int exO = sO[tid] - tO + blkOcc[blockIdx.x];
    int exC = sC[tid] - tC + blkCnt[blockIdx.x];
    int4 ps;
    ps.x = exC + locC[0]; ps.y = exC + locC[1];
    ps.z = exC + locC[2]; ps.w = exC + locC[3];
    pstart4[base >> 2] = ps;
    int psa[SCAN_I] = {ps.x, ps.y, ps.z, ps.w};
    #pragma unroll
    for (int i = 0; i < SCAN_I; ++i) {
        if (c[i] > 0) {
            int bin = base + i;
            int r   = exO + locO[i];
            rankstart[bin] = ((long long)r << 32)
                           | (long long)(unsigned)((c[i] << 20) | psa[i]);
            *(int2*)(&rowinfo[r]) = make_int2(psa[i], bin | (c[i] << 20));
        }
    }
}

// --- 3. fill: 4 points/thread; cnt==1 bins need NO atomic (single point -> p0) ---
__global__ __launch_bounds__(256) void k_fill(const int4* __restrict__ keys4,
                                              int* __restrict__ pstart,
                                              const long long* __restrict__ rankstart,
                                              int* __restrict__ perm,
                                              int4* __restrict__ rowinfo, int nq) {
    int t = blockIdx.x * blockDim.x + threadIdx.x;
    if (t >= nq) return;
    int4 kv = keys4[t];
    int ks[4] = {kv.x, kv.y, kv.z, kv.w};
    long long rs[4];
    #pragma unroll
    for (int i = 0; i < 4; ++i) rs[i] = rankstart[ks[i]];   // 4 loads in flight
    int pbase = t * 4;
    #pragma unroll
    for (int i = 0; i < 4; ++i) {
        int start = (int)(rs[i] & 0xFFFFF);
        int cnt   = (int)((rs[i] >> 20) & 0xFFF);
        int r     = (int)(rs[i] >> 32);
        int p     = pbase + i;
        if (cnt == 1) {
            ((int*)rowinfo)[r * 4 + 2] = p;              // sole point -> p0 slot
        } else {
            int pos = atomicAdd(&pstart[ks[i]], 1);
            int j = pos - start;
            if (j < 2) ((int*)rowinfo)[r * 4 + 2 + j] = p;   // p0 / p1 slots
            else       perm[pos] = p;
        }
    }
}

// --- 4. row-centric mean: 16 lanes (float4 each) per output row; nt streaming ---
__global__ __launch_bounds__(256) void k_mean(const f4* __restrict__ feats4,
                                              const int4* __restrict__ rowinfo,
                                              const int* __restrict__ perm,
                                              const int* __restrict__ m_dev,
                                              f4* __restrict__ out4) {
    int gid = blockIdx.x * blockDim.x + threadIdx.x;
    int row = gid >> 4;                          // output row
    int sub = gid & 15;                          // channels sub*4 .. sub*4+3
    if (row >= NBINS) return;
    float* out_coors = (float*)(out4 + (size_t)NBINS * 16);  // after 64M floats
    int M = *m_dev;
    if (row < M) {
        int4 info = rowinfo[row];
        int start = info.x;
        int bin   = info.y & 0xFFFFF;
        int cnt   = info.y >> 20;
        f4 s = __builtin_nontemporal_load(&feats4[(size_t)info.z * 16 + sub]); // p0
        if (cnt > 1) {
            f4 f = __builtin_nontemporal_load(&feats4[(size_t)info.w * 16 + sub]); // p1
            s += f;
        }
        if (cnt > 2) {                           // ~8% of rows: tail via perm
            int gbase = (threadIdx.x & 63) & ~15;
            for (int b0 = 2; b0 < cnt; b0 += 16) {
                int rem = cnt - b0;
                int lim = rem < 16 ? rem : 16;
                int pv  = (sub < lim) ? perm[start + b0 + sub] : 0;
                for (int j = 0; j < lim; ++j) {
                    int pj = __shfl(pv, gbase + j);
                    f4 f = __builtin_nontemporal_load(&feats4[(size_t)pj * 16 + sub]);
                    s += f;
                }
            }
        }
        float inv = 1.0f / (float)cnt;
        s *= inv;
        __builtin_nontemporal_store(s, &out4[(size_t)row * 16 + sub]);
        if (sub < 3) {
            int v = (sub == 0) ? bin / (GRIDN * GRIDN)
                  : (sub == 1) ? (bin / GRIDN) % GRIDN
                  :               bin % GRIDN;
            out_coors[row * 3 + sub] = (float)v;
        }
    } else {                                     // padding row
        f4 z = (f4){0.f, 0.f, 0.f, 0.f};
        __builtin_nontemporal_store(z, &out4[(size_t)row * 16 + sub]);
        if (sub < 3) out_coors[row * 3 + sub] = -1.f;
    }
}

extern "C" void kernel_launch(void* const* d_in, const int* in_sizes, int n_in,
                              void* d_out, int out_size, void* d_ws, size_t ws_size,
                              hipStream_t stream) {
    const float* feats = (const float*)d_in[0];
    const int*   coors = (const int*)d_in[1];
    float*       out   = (float*)d_out;
    int n = in_sizes[1] / 3;                     // 1,000,000 points

    // ws carve: keys | count | pstart | perm | rowinfo(int4) | rankstart(ll) | blk | m
    int*       keys      = (int*)d_ws;
    int*       count     = keys   + NPTS;
    int*       pstart    = count  + NBINS;
    int*       perm      = pstart + NBINS;
    int4*      rowinfo   = (int4*)(perm + NPTS);            // 16 MB, 16B-aligned
    long long* rankstart = (long long*)(rowinfo + NBINS);   // 8 MB
    int*       blkOcc    = (int*)(rankstart + NBINS);
    int*       blkCnt    = blkOcc + NBLK;
    int*       m_dev     = blkCnt + NBLK;

    hipMemsetAsync(count, 0, NBINS * sizeof(int), stream);

    int b  = 256;
    int nq = n >> 2;                             // 4 points per thread
    k_count<<<(nq + b - 1) / b, b, 0, stream>>>((const int4*)coors, (int4*)keys,
                                                count, nq);
    k_scan1<<<NBLK, SCAN_B, 0, stream>>>((const int4*)count, blkOcc, blkCnt);
    k_scan2<<<1, 1024, 0, stream>>>(blkOcc, blkCnt, m_dev);
    k_scan3<<<NBLK, SCAN_B, 0, stream>>>((const int4*)count, (int4*)pstart,
                                         blkOcc, blkCnt, rankstart, rowinfo);
    k_fill<<<(nq + b - 1) / b, b, 0, stream>>>((const int4*)keys, pstart, rankstart,
                                               perm, rowinfo, nq);
    k_mean<<<(NBINS * 16) / b, b, 0, stream>>>((const f4*)feats, rowinfo, perm,
                                               m_dev, (f4*)out);
}

// Round 5
// 532.873 us; speedup vs baseline: 1.0453x; 1.0089x over previous
//
#include <hip/hip_runtime.h>

#define NPTS   1000000
#define NFEAT  64
#define GRIDN  100
#define NBINS  1000000   // GRIDN^3

#define SCAN_B    256    // threads per scan block
#define SCAN_I    4      // items per thread
#define SCAN_TILE 1024   // SCAN_B * SCAN_I
#define NBLK      977    // ceil(NBINS / SCAN_TILE)
#define NBLK_PAD  1024   // tstate allocation (16B-align what follows)

typedef float f4 __attribute__((ext_vector_type(4)));
typedef int   i4 __attribute__((ext_vector_type(4)));   // clang vector: OK for
                                                        // __builtin_nontemporal_*

// tile-state word: [63:62]=status (0 none / 1 aggregate / 2 inclusive-prefix)
//                  [41:21]=O  [20:0]=C   (O,C <= 1M < 2^21)
#define PACK_ST(st, o, cc) ( ((unsigned long long)(st) << 62) \
                           | ((unsigned long long)(unsigned)(o) << 21) \
                           | (unsigned long long)(unsigned)(cc) )

// --- 1. histogram: 4 points/thread, i4 coalesced coors+keys ---
__global__ __launch_bounds__(256) void k_count(const i4* __restrict__ coors4,
                                               i4* __restrict__ keys4,
                                               int* __restrict__ count, int nq) {
    int t = blockIdx.x * blockDim.x + threadIdx.x;
    if (t >= nq) return;                          // nq = n/4
    i4 a = __builtin_nontemporal_load(&coors4[3 * t + 0]);
    i4 b = __builtin_nontemporal_load(&coors4[3 * t + 1]);
    i4 c = __builtin_nontemporal_load(&coors4[3 * t + 2]);
    int k0 = (a.x * GRIDN + a.y) * GRIDN + a.z;
    int k1 = (a.w * GRIDN + b.x) * GRIDN + b.y;
    int k2 = (b.z * GRIDN + b.w) * GRIDN + c.x;
    int k3 = (c.y * GRIDN + c.z) * GRIDN + c.w;
    i4 kv = {k0, k1, k2, k3};
    __builtin_nontemporal_store(kv, &keys4[t]);
    atomicAdd(&count[k0], 1);
    atomicAdd(&count[k1], 1);
    atomicAdd(&count[k2], 1);
    atomicAdd(&count[k3], 1);
}

// --- 2. single-pass dual scan (occupancy + count), wave-parallel lookback ---
// All NBLK=977 blocks are co-resident (2KB LDS, low VGPR -> 8 blk/CU -> 2048
// slots) and dispatched in blockIdx order, so waiting on predecessors is safe
// (same algorithm rocPRIM ships for single-pass scan on CDNA).
// rankstart[bin] = (rank << 32) | (cnt << 20) | start
// rowinfo[r]     = { start, bin | cnt<<20, p0 (by k_fill), p1 (by k_fill) }
__global__ __launch_bounds__(256) void k_scan(const i4* __restrict__ count4,
                                              i4* __restrict__ pstart4,
                                              unsigned long long* __restrict__ tstate,
                                              long long* __restrict__ rankstart,
                                              int4* __restrict__ rowinfo,
                                              int* __restrict__ m_dev) {
    __shared__ int sO[SCAN_B], sC[SCAN_B];
    __shared__ int sBaseO, sBaseC;
    int tid  = threadIdx.x;
    int blk  = blockIdx.x;
    int base = blk * SCAN_TILE + tid * SCAN_I;
    i4 v = {0, 0, 0, 0};
    if (base < NBINS) v = __builtin_nontemporal_load(&count4[base >> 2]);
    int c[SCAN_I] = {v.x, v.y, v.z, v.w};
    int locO[SCAN_I], locC[SCAN_I];
    int tO = 0, tC = 0;
    #pragma unroll
    for (int i = 0; i < SCAN_I; ++i) {
        locO[i] = tO; locC[i] = tC;
        tO += (c[i] > 0) ? 1 : 0;
        tC += c[i];
    }
    sO[tid] = tO; sC[tid] = tC;
    __syncthreads();
    for (int ofs = 1; ofs < SCAN_B; ofs <<= 1) {   // Hillis-Steele inclusive
        int a = 0, b = 0;
        if (tid >= ofs) { a = sO[tid - ofs]; b = sC[tid - ofs]; }
        __syncthreads();
        sO[tid] += a; sC[tid] += b;
        __syncthreads();
    }
    int aggO = sO[SCAN_B - 1], aggC = sC[SCAN_B - 1];   // tile totals
    if (blk == 0) {
        if (tid == 0) {
            __hip_atomic_store(&tstate[0], PACK_ST(2, aggO, aggC),
                               __ATOMIC_RELAXED, __HIP_MEMORY_SCOPE_AGENT);
            sBaseO = 0; sBaseC = 0;
        }
    } else {
        if (tid == 0)
            __hip_atomic_store(&tstate[blk], PACK_ST(1, aggO, aggC),
                               __ATOMIC_RELAXED, __HIP_MEMORY_SCOPE_AGENT);
        if (tid < 64) {                           // wave 0: parallel lookback
            int lane = tid;
            int exO = 0, exC = 0;
            int wend = blk - 1;
            for (;;) {
                int j = wend - lane;              // lane0 = nearest predecessor
                unsigned long long s = (j >= 0)
                    ? __hip_atomic_load(&tstate[j], __ATOMIC_RELAXED,
                                        __HIP_MEMORY_SCOPE_AGENT)
                    : PACK_ST(2, 0, 0);           // sentinel before tile 0
                unsigned st = (unsigned)(s >> 62);
                unsigned long long b2 = __ballot(st == 2u);
                unsigned long long b0 = __ballot(st == 0u);
                if (b2) {                         // inclusive prefix in window
                    int L = __ffsll((unsigned long long)b2) - 1;   // nearest
                    unsigned long long need =
                        (L >= 63) ? ~0ull : ((1ull << (L + 1)) - 1ull);
                    if (b0 & need) { __builtin_amdgcn_s_sleep(1); continue; }
                    int o  = (lane <= L) ? (int)((s >> 21) & 0x1FFFFF) : 0;
                    int cc = (lane <= L) ? (int)(s & 0x1FFFFF) : 0;
                    #pragma unroll
                    for (int ofs = 32; ofs > 0; ofs >>= 1) {
                        o  += __shfl_down(o, ofs);
                        cc += __shfl_down(cc, ofs);
                    }
                    exO += o; exC += cc;          // lane 0 holds totals
                    break;
                } else {
                    if (b0) { __builtin_amdgcn_s_sleep(1); continue; }
                    int o  = (int)((s >> 21) & 0x1FFFFF);   // all aggregates
                    int cc = (int)(s & 0x1FFFFF);
                    #pragma unroll
                    for (int ofs = 32; ofs > 0; ofs >>= 1) {
                        o  += __shfl_down(o, ofs);
                        cc += __shfl_down(cc, ofs);
                    }
                    exO += o; exC += cc;
                    wend -= 64;                   // consume window, keep walking
                }
            }
            if (lane == 0) {
                __hip_atomic_store(&tstate[blk], PACK_ST(2, exO + aggO, exC + aggC),
                                   __ATOMIC_RELAXED, __HIP_MEMORY_SCOPE_AGENT);
                sBaseO = exO; sBaseC = exC;
                if (blk == NBLK - 1) *m_dev = exO + aggO;   // total voxels M
            }
        }
    }
    __syncthreads();
    if (base >= NBINS) return;
    int exO = sBaseO + sO[tid] - tO;               // exclusive prefix, this thread
    int exC = sBaseC + sC[tid] - tC;
    i4 ps = {exC + locC[0], exC + locC[1], exC + locC[2], exC + locC[3]};
    pstart4[base >> 2] = ps;
    int psa[SCAN_I] = {ps.x, ps.y, ps.z, ps.w};
    #pragma unroll
    for (int i = 0; i < SCAN_I; ++i) {
        if (c[i] > 0) {
            int bin = base + i;
            int r   = exO + locO[i];
            rankstart[bin] = ((long long)r << 32)
                           | (long long)(unsigned)((c[i] << 20) | psa[i]);
            *(int2*)(&rowinfo[r]) = make_int2(psa[i], bin | (c[i] << 20));
        }
    }
}

// --- 3. fill: 4 points/thread; cnt==1 bins need NO atomic (single point -> p0) ---
__global__ __launch_bounds__(256) void k_fill(const i4* __restrict__ keys4,
                                              int* __restrict__ pstart,
                                              const long long* __restrict__ rankstart,
                                              int* __restrict__ perm,
                                              int4* __restrict__ rowinfo, int nq) {
    int t = blockIdx.x * blockDim.x + threadIdx.x;
    if (t >= nq) return;
    i4 kv = keys4[t];
    int ks[4] = {kv.x, kv.y, kv.z, kv.w};
    long long rs[4];
    #pragma unroll
    for (int i = 0; i < 4; ++i) rs[i] = rankstart[ks[i]];   // 4 loads in flight
    int pbase = t * 4;
    #pragma unroll
    for (int i = 0; i < 4; ++i) {
        int start = (int)(rs[i] & 0xFFFFF);
        int cnt   = (int)((rs[i] >> 20) & 0xFFF);
        int r     = (int)(rs[i] >> 32);
        int p     = pbase + i;
        if (cnt == 1) {
            ((int*)rowinfo)[r * 4 + 2] = p;              // sole point -> p0 slot
        } else {
            int pos = atomicAdd(&pstart[ks[i]], 1);
            int j = pos - start;
            if (j < 2) ((int*)rowinfo)[r * 4 + 2 + j] = p;   // p0 / p1 slots
            else       perm[pos] = p;
        }
    }
}

// --- 4. row-centric mean: 16 lanes (float4 each) per output row; nt streaming ---
__global__ __launch_bounds__(256) void k_mean(const f4* __restrict__ feats4,
                                              const int4* __restrict__ rowinfo,
                                              const int* __restrict__ perm,
                                              const int* __restrict__ m_dev,
                                              f4* __restrict__ out4) {
    int gid = blockIdx.x * blockDim.x + threadIdx.x;
    int row = gid >> 4;                          // output row
    int sub = gid & 15;                          // channels sub*4 .. sub*4+3
    if (row >= NBINS) return;
    float* out_coors = (float*)(out4 + (size_t)NBINS * 16);  // after 64M floats
    int M = *m_dev;
    if (row < M) {
        int4 info = rowinfo[row];
        int start = info.x;
        int bin   = info.y & 0xFFFFF;
        int cnt   = info.y >> 20;
        f4 s = __builtin_nontemporal_load(&feats4[(size_t)info.z * 16 + sub]); // p0
        if (cnt > 1) {
            f4 f = __builtin_nontemporal_load(&feats4[(size_t)info.w * 16 + sub]); // p1
            s += f;
        }
        if (cnt > 2) {                           // ~8% of rows: tail via perm
            int gbase = (threadIdx.x & 63) & ~15;
            for (int b0 = 2; b0 < cnt; b0 += 16) {
                int rem = cnt - b0;
                int lim = rem < 16 ? rem : 16;
                int pv  = (sub < lim) ? perm[start + b0 + sub] : 0;
                for (int j = 0; j < lim; ++j) {
                    int pj = __shfl(pv, gbase + j);
                    f4 f = __builtin_nontemporal_load(&feats4[(size_t)pj * 16 + sub]);
                    s += f;
                }
            }
        }
        float inv = 1.0f / (float)cnt;
        s *= inv;
        __builtin_nontemporal_store(s, &out4[(size_t)row * 16 + sub]);
        if (sub < 3) {
            int v = (sub == 0) ? bin / (GRIDN * GRIDN)
                  : (sub == 1) ? (bin / GRIDN) % GRIDN
                  :               bin % GRIDN;
            out_coors[row * 3 + sub] = (float)v;
        }
    } else {                                     // padding row
        f4 z = (f4){0.f, 0.f, 0.f, 0.f};
        __builtin_nontemporal_store(z, &out4[(size_t)row * 16 + sub]);
        if (sub < 3) out_coors[row * 3 + sub] = -1.f;
    }
}

extern "C" void kernel_launch(void* const* d_in, const int* in_sizes, int n_in,
                              void* d_out, int out_size, void* d_ws, size_t ws_size,
                              hipStream_t stream) {
    const float* feats = (const float*)d_in[0];
    const int*   coors = (const int*)d_in[1];
    float*       out   = (float*)d_out;
    int n = in_sizes[1] / 3;                     // 1,000,000 points

    // ws carve (all 16B-aligned section starts):
    // keys(4MB) | count(4MB) | tstate(8KB) | pstart(4MB) | perm(4MB)
    // | rowinfo int4(16MB) | rankstart ll(8MB) | m_dev
    int*                keys      = (int*)d_ws;
    int*                count     = keys   + NPTS;
    unsigned long long* tstate    = (unsigned long long*)(count + NBINS);
    int*                pstart    = (int*)(tstate + NBLK_PAD);
    int*                perm      = pstart + NBINS;
    int4*               rowinfo   = (int4*)(perm + NPTS);
    long long*          rankstart = (long long*)(rowinfo + NBINS);
    int*                m_dev     = (int*)(rankstart + NBINS);

    // zero count + tile states in one memset (adjacent)
    (void)hipMemsetAsync(count, 0,
                   NBINS * sizeof(int) + NBLK_PAD * sizeof(unsigned long long),
                   stream);

    int b  = 256;
    int nq = n >> 2;                             // 4 points per thread
    k_count<<<(nq + b - 1) / b, b, 0, stream>>>((const i4*)coors, (i4*)keys,
                                                count, nq);
    k_scan<<<NBLK, SCAN_B, 0, stream>>>((const i4*)count, (i4*)pstart, tstate,
                                        rankstart, rowinfo, m_dev);
    k_fill<<<(nq + b - 1) / b, b, 0, stream>>>((const i4*)keys, pstart, rankstart,
                                               perm, rowinfo, nq);
    k_mean<<<(NBINS * 16) / b, b, 0, stream>>>((const f4*)feats, rowinfo, perm,
                                               m_dev, (f4*)out);
}